// Round 2
// baseline (2301.458 us; speedup 1.0000x reference)
//
#include <hip/hip_runtime.h>
#include <cstdint>
#include <cmath>

// Transformer encoder: B=256, L=100, D=512, F=2048, NL=4, H=8, hd=64.
// GEMMs: bf16 MFMA (fp32 accum). Residual stream bf16; LN/softmax fp32.
// Workspace budget ~156 MB: XB 26.2 + BIGB 104.9 (qkv|AOUT|h) + PE 0.2 + W 25.2.
// fp32 GEMM outputs (pre-LN) live in d_out.

#define NLAYERS 4
#define BB 256
#define LL 100
#define DD 512
#define FF 2048
#define NH 8
#define HD 64
#define MM (BB*LL)   // 25600 rows

typedef __bf16 bf16;
typedef bf16 bf16x8 __attribute__((ext_vector_type(8)));
typedef bf16 bf16x4 __attribute__((ext_vector_type(4)));
typedef float f32x4 __attribute__((ext_vector_type(4)));

__device__ __forceinline__ void load16(const void* g, void* l) {
  __builtin_amdgcn_global_load_lds(
      (const __attribute__((address_space(1))) void*)g,
      (__attribute__((address_space(3))) void*)l, 16, 0, 0);
}

// ---------------- positional encoding table [L][D] ----------------
__global__ void pe_kernel(float* __restrict__ pe) {
  const int idx = blockIdx.x * 256 + threadIdx.x;   // 51200 total
  if (idx >= LL * DD) return;
  const int l = idx >> 9, d = idx & 511;
  const int i = d >> 1;
  const float div = expf((float)(2 * i) * (-9.210340371976184f / 512.f)); // -ln(10000)/D
  const float ang = (float)l * div;
  pe[idx] = (d & 1) ? cosf(ang) : sinf(ang);
}

// ---------------- xb = bf16(2*x + pe) ----------------
__global__ __launch_bounds__(256) void x0_kernel(
    const float* __restrict__ xin, const float* __restrict__ pe,
    bf16* __restrict__ XB) {
  const size_t f = (size_t)blockIdx.x * 256 + threadIdx.x;  // float4 index
  const size_t e = f << 2;
  const int col  = (int)(e & 511);
  const int prow = (int)((e >> 9) % LL);
  const float4 xv = *(const float4*)(xin + e);
  const float4 pv = *(const float4*)(pe + (size_t)prow * DD + col);
  bf16x4 pk;
  pk[0] = (bf16)(2.f * xv.x + pv.x);
  pk[1] = (bf16)(2.f * xv.y + pv.y);
  pk[2] = (bf16)(2.f * xv.z + pv.z);
  pk[3] = (bf16)(2.f * xv.w + pv.w);
  *(bf16x4*)(XB + e) = pk;
}

// ---------------- weight cast + transpose: [K][N] f32 -> [N][K] bf16 ----------------
__global__ void transpose_cast(const float* __restrict__ src, bf16* __restrict__ dst,
                               int K, int N) {
  __shared__ float tile[32][33];
  const int z = blockIdx.z;
  src += (size_t)z * K * N;
  dst += (size_t)z * K * N;
  const int k0 = blockIdx.y * 32, n0 = blockIdx.x * 32;
  const int tx = threadIdx.x, ty = threadIdx.y;  // (32,8)
  #pragma unroll
  for (int i = 0; i < 32; i += 8)
    tile[ty + i][tx] = src[(size_t)(k0 + ty + i) * N + n0 + tx];
  __syncthreads();
  #pragma unroll
  for (int i = 0; i < 32; i += 8)
    dst[(size_t)(n0 + ty + i) * K + k0 + tx] = (bf16)tile[tx][ty + i];
}

// ---------------- bf16 MFMA GEMM: C[M,N] = A[M,K] @ Bt[N,K]^T (+bias)(+relu) ----------
// m97 structure: 128x128 tile, 4 waves (2x2), 16x16x32 mfma, 4x4 frags/wave,
// global_load_lds width-16 staging, BK=32.
template<int OUT_BF16, int RELU>
__global__ __launch_bounds__(256) void gemm_bt(
    const bf16* __restrict__ A, const bf16* __restrict__ Bt,
    const float* __restrict__ bias, void* __restrict__ Cv,
    int M, int N, int K) {
  __shared__ __align__(16) bf16 sA[128 * 32];
  __shared__ __align__(16) bf16 sB[128 * 32];
  const int tid = threadIdx.x;
  const int w = tid >> 6, lane = tid & 63;
  const int wr = w >> 1, wc = w & 1;
  const size_t bm = (size_t)blockIdx.y << 7;
  const size_t bn = (size_t)blockIdx.x << 7;
  const int lr = lane & 15, lk = (lane >> 4) << 3;

  f32x4 acc[4][4] = {};

  const int r0 = tid >> 2;             // 0..63
  const int c0 = (tid & 3) << 3;       // 0,8,16,24
  const bf16* ga0 = A  + (bm + r0) * K + c0;
  const bf16* ga1 = A  + (bm + 64 + r0) * K + c0;
  const bf16* gb0 = Bt + (bn + r0) * K + c0;
  const bf16* gb1 = Bt + (bn + 64 + r0) * K + c0;
  bf16* la0 = sA + (w << 9);
  bf16* la1 = sA + 2048 + (w << 9);
  bf16* lb0 = sB + (w << 9);
  bf16* lb1 = sB + 2048 + (w << 9);

  for (int k0 = 0; k0 < K; k0 += 32) {
    __syncthreads();                 // previous iter's readers done
    load16(ga0 + k0, la0);
    load16(ga1 + k0, la1);
    load16(gb0 + k0, lb0);
    load16(gb1 + k0, lb1);
    __syncthreads();                 // vmcnt drained before barrier

    bf16x8 af[4], bv[4];
    #pragma unroll
    for (int m = 0; m < 4; ++m)
      af[m] = *(const bf16x8*)&sA[((wr << 6) + (m << 4) + lr) * 32 + lk];
    #pragma unroll
    for (int n = 0; n < 4; ++n)
      bv[n] = *(const bf16x8*)&sB[((wc << 6) + (n << 4) + lr) * 32 + lk];
    #pragma unroll
    for (int m = 0; m < 4; ++m)
      #pragma unroll
      for (int n = 0; n < 4; ++n)
        acc[m][n] = __builtin_amdgcn_mfma_f32_16x16x32_bf16(af[m], bv[n], acc[m][n], 0, 0, 0);
  }

  // epilogue: D row = (lane>>4)*4 + j within 16-block, col = lane&15
  const int row0 = (int)bm + (wr << 6) + ((lane >> 4) << 2);
  const int col0 = (int)bn + (wc << 6) + lr;
  #pragma unroll
  for (int n = 0; n < 4; ++n) {
    const int col = col0 + (n << 4);
    const float bvv = bias ? bias[col] : 0.f;
    #pragma unroll
    for (int m = 0; m < 4; ++m) {
      const int row = row0 + (m << 4);
      #pragma unroll
      for (int j = 0; j < 4; ++j) {
        float v = acc[m][n][j] + bvv;
        if (RELU) v = fmaxf(v, 0.f);
        if (OUT_BF16) ((bf16*)Cv)[(size_t)(row + j) * N + col] = (bf16)v;
        else          ((float*)Cv)[(size_t)(row + j) * N + col] = v;
      }
    }
  }
}

// ---------------- fused attention: one block per (b,h) ----------------
__global__ __launch_bounds__(128) void attn_kernel(
    const bf16* __restrict__ qkv, const int* __restrict__ mask,
    bf16* __restrict__ aout) {
  __shared__ float sK[LL * HD];
  __shared__ float sV[LL * HD];
  __shared__ int   sM[LL];
  const int bh = blockIdx.x;
  const int b = bh >> 3, h = bh & 7;
  const int tid = threadIdx.x;

  for (int ch = tid; ch < LL * 8; ch += 128) {   // 8 chunks of 8 bf16 per row
    const int l = ch >> 3, u = ch & 7;
    const bf16* kp = qkv + ((size_t)(b * LL + l)) * (3 * DD) + DD + h * HD + (u << 3);
    bf16x8 kv = *(const bf16x8*)kp;
    bf16x8 vv = *(const bf16x8*)(kp + DD);
    #pragma unroll
    for (int j = 0; j < 8; ++j) {
      sK[(l << 6) + (u << 3) + j] = (float)kv[j];
      sV[(l << 6) + (u << 3) + j] = (float)vv[j];
    }
  }
  if (tid < LL) sM[tid] = mask[b * LL + tid];
  __syncthreads();

  if (tid >= LL) return;
  float q[HD];
  {
    const bf16* qp = qkv + ((size_t)(b * LL + tid)) * (3 * DD) + h * HD;
    #pragma unroll
    for (int u = 0; u < 8; ++u) {
      bf16x8 v = *(const bf16x8*)(qp + (u << 3));
      #pragma unroll
      for (int j = 0; j < 8; ++j) q[(u << 3) + j] = (float)v[j];
    }
  }
  float o[HD];
  #pragma unroll
  for (int d = 0; d < HD; ++d) o[d] = 0.f;
  float mx = -__builtin_inff(), ssum = 0.f;

  #pragma unroll 1
  for (int k = 0; k < LL; ++k) {
    if (sM[k] == 0) continue;
    const float* kr = &sK[k << 6];
    float part[8] = {0, 0, 0, 0, 0, 0, 0, 0};
    #pragma unroll
    for (int u = 0; u < 8; ++u)
      #pragma unroll
      for (int j = 0; j < 8; ++j)
        part[j] = fmaf(q[u * 8 + j], kr[u * 8 + j], part[j]);
    const float dot = ((part[0] + part[1]) + (part[2] + part[3])) +
                      ((part[4] + part[5]) + (part[6] + part[7]));
    if (dot > mx) {
      const float c = __expf(mx - dot);
      ssum *= c;
      #pragma unroll
      for (int d = 0; d < HD; ++d) o[d] *= c;
      mx = dot;
    }
    const float p = __expf(dot - mx);
    ssum += p;
    const float* vr = &sV[k << 6];
    #pragma unroll
    for (int d = 0; d < HD; ++d) o[d] = fmaf(p, vr[d], o[d]);
  }
  const float inv = 1.f / ssum;
  bf16* op = aout + ((size_t)(b * LL + tid)) * DD + h * HD;
  #pragma unroll
  for (int u = 0; u < 8; ++u) {
    bf16x8 pk;
    #pragma unroll
    for (int j = 0; j < 8; ++j) pk[j] = (bf16)(o[(u << 3) + j] * inv);
    *(bf16x8*)(op + (u << 3)) = pk;
  }
}

// ---------------- residual add + LayerNorm (one wave per row) ----------------
// z = Y(fp32) + RES(bf16); out: XB(bf16) always, XF(fp32) if WRITE_F32.
template<int WRITE_F32>
__global__ __launch_bounds__(64) void ln_kernel(
    const float* __restrict__ Y, const bf16* __restrict__ RES,
    const float* __restrict__ g, const float* __restrict__ bt,
    bf16* __restrict__ XB, float* __restrict__ XF) {
  const int row = blockIdx.x;
  const int lane = threadIdx.x;
  const size_t base = (size_t)row * DD + lane * 8;
  const float4 a0 = *(const float4*)(Y + base);
  const float4 a1 = *(const float4*)(Y + base + 4);
  const bf16x8 rv = *(const bf16x8*)(RES + base);
  float z[8];
  z[0] = a0.x + (float)rv[0]; z[1] = a0.y + (float)rv[1];
  z[2] = a0.z + (float)rv[2]; z[3] = a0.w + (float)rv[3];
  z[4] = a1.x + (float)rv[4]; z[5] = a1.y + (float)rv[5];
  z[6] = a1.z + (float)rv[6]; z[7] = a1.w + (float)rv[7];
  float s = 0.f, s2 = 0.f;
  #pragma unroll
  for (int j = 0; j < 8; ++j) { s += z[j]; s2 = fmaf(z[j], z[j], s2); }
  #pragma unroll
  for (int off = 32; off > 0; off >>= 1) {
    s  += __shfl_xor(s, off, 64);
    s2 += __shfl_xor(s2, off, 64);
  }
  const float mu = s * (1.f / 512.f);
  const float var = s2 * (1.f / 512.f) - mu * mu;
  const float inv = rsqrtf(var + 1e-5f);
  const int c = lane * 8;
  const float4 g0 = *(const float4*)(g + c),  g1 = *(const float4*)(g + c + 4);
  const float4 b0 = *(const float4*)(bt + c), b1 = *(const float4*)(bt + c + 4);
  float ov[8];
  ov[0] = (z[0] - mu) * inv * g0.x + b0.x; ov[1] = (z[1] - mu) * inv * g0.y + b0.y;
  ov[2] = (z[2] - mu) * inv * g0.z + b0.z; ov[3] = (z[3] - mu) * inv * g0.w + b0.w;
  ov[4] = (z[4] - mu) * inv * g1.x + b1.x; ov[5] = (z[5] - mu) * inv * g1.y + b1.y;
  ov[6] = (z[6] - mu) * inv * g1.z + b1.z; ov[7] = (z[7] - mu) * inv * g1.w + b1.w;
  bf16x8 pk;
  #pragma unroll
  for (int j = 0; j < 8; ++j) pk[j] = (bf16)ov[j];
  *(bf16x8*)(XB + base) = pk;
  if (WRITE_F32) {
    *(float4*)(XF + base)     = make_float4(ov[0], ov[1], ov[2], ov[3]);
    *(float4*)(XF + base + 4) = make_float4(ov[4], ov[5], ov[6], ov[7]);
  }
}

extern "C" void kernel_launch(void* const* d_in, const int* in_sizes, int n_in,
                              void* d_out, int out_size, void* d_ws, size_t ws_size,
                              hipStream_t stream) {
  const float* x_in   = (const float*)d_in[0];
  const int*   mask   = (const int*)d_in[1];
  const float* qkv_w  = (const float*)d_in[2];
  const float* fc_w   = (const float*)d_in[3];
  const float* fc_b   = (const float*)d_in[4];
  const float* ln1_g  = (const float*)d_in[5];
  const float* ln1_b  = (const float*)d_in[6];
  const float* ln2_g  = (const float*)d_in[7];
  const float* ln2_b  = (const float*)d_in[8];
  const float* ffn_w1 = (const float*)d_in[9];
  const float* ffn_b1 = (const float*)d_in[10];
  const float* ffn_w2 = (const float*)d_in[11];
  const float* ffn_b2 = (const float*)d_in[12];

  char* ws = (char*)d_ws;
  size_t off = 0;
  auto alloc = [&](size_t bytes) -> void* {
    off = (off + 255) & ~(size_t)255;
    void* p = ws + off;
    off += bytes;
    return p;
  };
  bf16*  XB   = (bf16*) alloc((size_t)MM * DD * 2);        // bf16 residual stream
  bf16*  BIGB = (bf16*) alloc((size_t)MM * FF * 2);        // qkv [M,1536] | h [M,2048]
  float* PE   = (float*)alloc((size_t)LL * DD * 4);
  bf16*  WQKV = (bf16*) alloc((size_t)NLAYERS * DD * 3 * DD * 2);  // [1536][512] per layer
  bf16*  WFC  = (bf16*) alloc((size_t)NLAYERS * DD * DD * 2);      // [512][512]
  bf16*  W1T  = (bf16*) alloc((size_t)NLAYERS * DD * FF * 2);      // [2048][512]
  bf16*  W2T  = (bf16*) alloc((size_t)NLAYERS * FF * DD * 2);      // [512][2048]
  bf16*  AOUT = BIGB + (size_t)MM * (3 * DD);              // tail of BIGB: [M,512]
  float* Y    = (float*)d_out;                             // fp32 pre-LN GEMM out
  (void)ws_size; (void)in_sizes; (void)n_in; (void)out_size;

  pe_kernel<<<200, 256, 0, stream>>>(PE);
  transpose_cast<<<dim3(48, 16, NLAYERS), dim3(32, 8), 0, stream>>>(qkv_w,  WQKV, 512, 1536);
  transpose_cast<<<dim3(16, 16, NLAYERS), dim3(32, 8), 0, stream>>>(fc_w,   WFC,  512, 512);
  transpose_cast<<<dim3(64, 16, NLAYERS), dim3(32, 8), 0, stream>>>(ffn_w1, W1T,  512, 2048);
  transpose_cast<<<dim3(16, 64, NLAYERS), dim3(32, 8), 0, stream>>>(ffn_w2, W2T,  2048, 512);
  x0_kernel<<<12800, 256, 0, stream>>>(x_in, PE, XB);

  for (int i = 0; i < NLAYERS; ++i) {
    // qkv = xb @ qkv_w  -> bf16 [M,1536]
    gemm_bt<1, 0><<<dim3(12, 200), 256, 0, stream>>>(
        XB, WQKV + (size_t)i * DD * 3 * DD, nullptr, BIGB, MM, 3 * DD, DD);
    // attention -> bf16 [M,512] (AOUT, aliased tail of BIGB)
    attn_kernel<<<BB * NH, 128, 0, stream>>>(BIGB, mask, AOUT);
    // attn proj + bias -> fp32 Y (=d_out)
    gemm_bt<0, 0><<<dim3(4, 200), 256, 0, stream>>>(
        AOUT, WFC + (size_t)i * DD * DD, fc_b + i * DD, Y, MM, DD, DD);
    // x = LN(Y + x)  (bf16 stream)
    ln_kernel<0><<<MM, 64, 0, stream>>>(Y, XB, ln1_g + i * DD, ln1_b + i * DD, XB, nullptr);
    // h = relu(x @ w1 + b1) -> bf16 [M,2048] (overwrites qkv+AOUT, both dead)
    gemm_bt<1, 1><<<dim3(16, 200), 256, 0, stream>>>(
        XB, W1T + (size_t)i * DD * FF, ffn_b1 + i * FF, BIGB, MM, FF, DD);
    // y = h @ w2 + b2 -> fp32 Y (=d_out)
    gemm_bt<0, 0><<<dim3(4, 200), 256, 0, stream>>>(
        BIGB, W2T + (size_t)i * FF * DD, ffn_b2 + i * DD, Y, MM, DD, FF);
    // x = LN(Y + x); final layer also writes fp32 d_out (in-place on Y rows)
    if (i == NLAYERS - 1)
      ln_kernel<1><<<MM, 64, 0, stream>>>(Y, XB, ln2_g + i * DD, ln2_b + i * DD,
                                          XB, (float*)d_out);
    else
      ln_kernel<0><<<MM, 64, 0, stream>>>(Y, XB, ln2_g + i * DD, ln2_b + i * DD, XB, nullptr);
  }
}

// Round 3
// 1506.592 us; speedup vs baseline: 1.5276x; 1.5276x over previous
//
#include <hip/hip_runtime.h>
#include <cstdint>
#include <cmath>

// Transformer encoder: B=256, L=100, D=512, F=2048, NL=4, H=8, hd=64.
// GEMMs + attention: bf16 MFMA (fp32 accum). Residual stream bf16; LN/softmax fp32.

#define NLAYERS 4
#define BB 256
#define LL 100
#define DD 512
#define FF 2048
#define NH 8
#define HD 64
#define MM (BB*LL)   // 25600 rows
#define ATT_R 112    // L padded to 7*16
#define ATT_K 128    // key dim padded to 4*32 for PV k-steps

typedef __bf16 bf16;
typedef bf16 bf16x8 __attribute__((ext_vector_type(8)));
typedef bf16 bf16x4 __attribute__((ext_vector_type(4)));
typedef float f32x4 __attribute__((ext_vector_type(4)));

__device__ __forceinline__ void load16(const void* g, void* l) {
  __builtin_amdgcn_global_load_lds(
      (const __attribute__((address_space(1))) void*)g,
      (__attribute__((address_space(3))) void*)l, 16, 0, 0);
}

// ---------------- positional encoding table [L][D] ----------------
__global__ void pe_kernel(float* __restrict__ pe) {
  const int idx = blockIdx.x * 256 + threadIdx.x;
  if (idx >= LL * DD) return;
  const int l = idx >> 9, d = idx & 511;
  const int i = d >> 1;
  const float div = expf((float)(2 * i) * (-9.210340371976184f / 512.f));
  const float ang = (float)l * div;
  pe[idx] = (d & 1) ? cosf(ang) : sinf(ang);
}

// ---------------- xb = bf16(2*x + pe) ----------------
__global__ __launch_bounds__(256) void x0_kernel(
    const float* __restrict__ xin, const float* __restrict__ pe,
    bf16* __restrict__ XB) {
  const size_t f = (size_t)blockIdx.x * 256 + threadIdx.x;
  const size_t e = f << 2;
  const int col  = (int)(e & 511);
  const int prow = (int)((e >> 9) % LL);
  const float4 xv = *(const float4*)(xin + e);
  const float4 pv = *(const float4*)(pe + (size_t)prow * DD + col);
  bf16x4 pk;
  pk[0] = (bf16)(2.f * xv.x + pv.x);
  pk[1] = (bf16)(2.f * xv.y + pv.y);
  pk[2] = (bf16)(2.f * xv.z + pv.z);
  pk[3] = (bf16)(2.f * xv.w + pv.w);
  *(bf16x4*)(XB + e) = pk;
}

// ---------------- weight cast + transpose: [K][N] f32 -> [N][K] bf16 ----------------
__global__ void transpose_cast(const float* __restrict__ src, bf16* __restrict__ dst,
                               int K, int N) {
  __shared__ float tile[32][33];
  const int z = blockIdx.z;
  src += (size_t)z * K * N;
  dst += (size_t)z * K * N;
  const int k0 = blockIdx.y * 32, n0 = blockIdx.x * 32;
  const int tx = threadIdx.x, ty = threadIdx.y;
  #pragma unroll
  for (int i = 0; i < 32; i += 8)
    tile[ty + i][tx] = src[(size_t)(k0 + ty + i) * N + n0 + tx];
  __syncthreads();
  #pragma unroll
  for (int i = 0; i < 32; i += 8)
    dst[(size_t)(n0 + ty + i) * K + k0 + tx] = (bf16)tile[tx][ty + i];
}

// ---------------- bf16 MFMA GEMM (m97 structure) ----------------
template<int OUT_BF16, int RELU>
__global__ __launch_bounds__(256) void gemm_bt(
    const bf16* __restrict__ A, const bf16* __restrict__ Bt,
    const float* __restrict__ bias, void* __restrict__ Cv,
    int M, int N, int K) {
  __shared__ __align__(16) bf16 sA[128 * 32];
  __shared__ __align__(16) bf16 sB[128 * 32];
  const int tid = threadIdx.x;
  const int w = tid >> 6, lane = tid & 63;
  const int wr = w >> 1, wc = w & 1;
  const size_t bm = (size_t)blockIdx.y << 7;
  const size_t bn = (size_t)blockIdx.x << 7;
  const int lr = lane & 15, lk = (lane >> 4) << 3;

  f32x4 acc[4][4] = {};

  const int r0 = tid >> 2;
  const int c0 = (tid & 3) << 3;
  const bf16* ga0 = A  + (bm + r0) * K + c0;
  const bf16* ga1 = A  + (bm + 64 + r0) * K + c0;
  const bf16* gb0 = Bt + (bn + r0) * K + c0;
  const bf16* gb1 = Bt + (bn + 64 + r0) * K + c0;
  bf16* la0 = sA + (w << 9);
  bf16* la1 = sA + 2048 + (w << 9);
  bf16* lb0 = sB + (w << 9);
  bf16* lb1 = sB + 2048 + (w << 9);

  for (int k0 = 0; k0 < K; k0 += 32) {
    __syncthreads();
    load16(ga0 + k0, la0);
    load16(ga1 + k0, la1);
    load16(gb0 + k0, lb0);
    load16(gb1 + k0, lb1);
    __syncthreads();

    bf16x8 af[4], bv[4];
    #pragma unroll
    for (int m = 0; m < 4; ++m)
      af[m] = *(const bf16x8*)&sA[((wr << 6) + (m << 4) + lr) * 32 + lk];
    #pragma unroll
    for (int n = 0; n < 4; ++n)
      bv[n] = *(const bf16x8*)&sB[((wc << 6) + (n << 4) + lr) * 32 + lk];
    #pragma unroll
    for (int m = 0; m < 4; ++m)
      #pragma unroll
      for (int n = 0; n < 4; ++n)
        acc[m][n] = __builtin_amdgcn_mfma_f32_16x16x32_bf16(af[m], bv[n], acc[m][n], 0, 0, 0);
  }

  const int row0 = (int)bm + (wr << 6) + ((lane >> 4) << 2);
  const int col0 = (int)bn + (wc << 6) + lr;
  #pragma unroll
  for (int n = 0; n < 4; ++n) {
    const int col = col0 + (n << 4);
    const float bvv = bias ? bias[col] : 0.f;
    #pragma unroll
    for (int m = 0; m < 4; ++m) {
      const int row = row0 + (m << 4);
      #pragma unroll
      for (int j = 0; j < 4; ++j) {
        float v = acc[m][n][j] + bvv;
        if (RELU) v = fmaxf(v, 0.f);
        if (OUT_BF16) ((bf16*)Cv)[(size_t)(row + j) * N + col] = (bf16)v;
        else          ((float*)Cv)[(size_t)(row + j) * N + col] = v;
      }
    }
  }
}

// ---------------- MFMA attention: one block (4 waves) per (b,h) ----------------
// Q,K in LDS row-major [112][64] bf16, XOR-swizzled rows ( ^ (row&7)<<4 ).
// V transposed in LDS: Vt[64][136] bf16 (stride 272B -> 2-way banks, free).
// P in LDS [112][128] bf16, swizzled rows.
// Phase1: S=Q@K^T per wave (m-frags {w,w+4}); exact softmax; P to LDS.
// Phase2: O=P@V, wave w owns d-cols [16w,16w+16).
__global__ __launch_bounds__(256) void attn_mfma(
    const bf16* __restrict__ qkv, const int* __restrict__ mask,
    bf16* __restrict__ aout) {
  __shared__ __align__(16) bf16 sQ[ATT_R * 64];
  __shared__ __align__(16) bf16 sK[ATT_R * 64];
  __shared__ __align__(16) bf16 sVt[64 * 136];
  __shared__ __align__(16) bf16 sP[ATT_R * ATT_K];
  __shared__ int sM[ATT_R];
  const int bh = blockIdx.x, b = bh >> 3, h = bh & 7;
  const int tid = threadIdx.x, w = tid >> 6, lane = tid & 63;
  const int lr = lane & 15;              // A/B frag row|col ; C/D col
  const int lk = (lane >> 4) << 3;       // A/B frag k-offset (elems)
  const int g  = lane >> 4;              // C/D row group

  // zero LDS (pads must be 0)
  for (int i = tid; i < ATT_R * 64 / 8; i += 256) { ((int4*)sQ)[i] = int4{0,0,0,0}; ((int4*)sK)[i] = int4{0,0,0,0}; }
  for (int i = tid; i < 64 * 136 / 8; i += 256) ((int4*)sVt)[i] = int4{0,0,0,0};
  for (int i = tid; i < ATT_R * ATT_K / 8; i += 256) ((int4*)sP)[i] = int4{0,0,0,0};
  __syncthreads();

  // stage Q,K (swizzled), V->Vt (transpose), mask
  const bf16* base = qkv + (size_t)(b * LL) * (3 * DD) + h * HD;
  for (int c = tid; c < LL * 8; c += 256) {       // 800 chunks of 8 bf16
    const int l = c >> 3, u = c & 7;
    const bf16x8 qv = *(const bf16x8*)(base + (size_t)l * (3 * DD) + u * 8);
    const bf16x8 kv = *(const bf16x8*)(base + (size_t)l * (3 * DD) + DD + u * 8);
    const bf16x8 vv = *(const bf16x8*)(base + (size_t)l * (3 * DD) + 2 * DD + u * 8);
    const int qb = (l * 128 + u * 16) ^ ((l & 7) << 4);
    *(bf16x8*)((char*)sQ + qb) = qv;
    *(bf16x8*)((char*)sK + qb) = kv;
    #pragma unroll
    for (int j = 0; j < 8; ++j) sVt[(u * 8 + j) * 136 + l] = vv[j];
  }
  if (tid < ATT_R) sM[tid] = (tid < LL) ? mask[b * LL + tid] : 0;
  __syncthreads();

  // ---- phase 1: S = Q K^T, softmax, P -> LDS ----
  #pragma unroll
  for (int fi = 0; fi < 2; ++fi) {
    const int fm = w + fi * 4;
    if (fm >= 7) continue;
    const int ar = fm * 16 + lr;
    const int abase = ar * 128;
    const int aswz = (ar & 7) << 4;
    const bf16x8 a0 = *(const bf16x8*)((char*)sQ + ((abase + lk * 2) ^ aswz));
    const bf16x8 a1 = *(const bf16x8*)((char*)sQ + ((abase + 64 + lk * 2) ^ aswz));
    f32x4 s[7];
    #pragma unroll
    for (int fn = 0; fn < 7; ++fn) {
      const int br = fn * 16 + lr;
      const int bswz = (br & 7) << 4;
      const bf16x8 b0 = *(const bf16x8*)((char*)sK + ((br * 128 + lk * 2) ^ bswz));
      const bf16x8 b1 = *(const bf16x8*)((char*)sK + ((br * 128 + 64 + lk * 2) ^ bswz));
      f32x4 acc = {};
      acc = __builtin_amdgcn_mfma_f32_16x16x32_bf16(a0, b0, acc, 0, 0, 0);
      acc = __builtin_amdgcn_mfma_f32_16x16x32_bf16(a1, b1, acc, 0, 0, 0);
      s[fn] = acc;
    }
    // mask (col = fn*16 + lr)
    #pragma unroll
    for (int fn = 0; fn < 7; ++fn) {
      if (sM[fn * 16 + lr] == 0) {
        s[fn][0] = -INFINITY; s[fn][1] = -INFINITY;
        s[fn][2] = -INFINITY; s[fn][3] = -INFINITY;
      }
    }
    // row max / exp / sum / normalize
    float m4[4], sm[4];
    #pragma unroll
    for (int j = 0; j < 4; ++j) {
      float m = s[0][j];
      #pragma unroll
      for (int fn = 1; fn < 7; ++fn) m = fmaxf(m, s[fn][j]);
      #pragma unroll
      for (int off = 1; off < 16; off <<= 1) m = fmaxf(m, __shfl_xor(m, off, 64));
      m4[j] = m;
      float t = 0.f;
      #pragma unroll
      for (int fn = 0; fn < 7; ++fn) { const float p = __expf(s[fn][j] - m); s[fn][j] = p; t += p; }
      #pragma unroll
      for (int off = 1; off < 16; off <<= 1) t += __shfl_xor(t, off, 64);
      sm[j] = 1.f / t;
    }
    // write P (bf16, swizzled): row = fm*16 + 4g + j, col = fn*16 + lr
    #pragma unroll
    for (int fn = 0; fn < 7; ++fn) {
      const int k = fn * 16 + lr;
      #pragma unroll
      for (int j = 0; j < 4; ++j) {
        const int r = fm * 16 + 4 * g + j;
        const int byte = (r * 256 + k * 2) ^ ((r & 7) << 4);
        *(bf16*)((char*)sP + byte) = (bf16)(s[fn][j] * sm[j]);
      }
    }
  }
  __syncthreads();

  // ---- phase 2: O = P V ; wave w -> d cols [16w, 16w+16) ----
  bf16x8 bV[4];
  #pragma unroll
  for (int ks = 0; ks < 4; ++ks)
    bV[ks] = *(const bf16x8*)((char*)sVt + ((w * 16 + lr) * 272 + ks * 64 + lk * 2));
  #pragma unroll
  for (int fm = 0; fm < 7; ++fm) {
    f32x4 acc = {};
    const int ar = fm * 16 + lr;
    const int aswz = (ar & 7) << 4;
    #pragma unroll
    for (int ks = 0; ks < 4; ++ks) {
      const bf16x8 aP = *(const bf16x8*)((char*)sP + ((ar * 256 + ks * 64 + lk * 2) ^ aswz));
      acc = __builtin_amdgcn_mfma_f32_16x16x32_bf16(aP, bV[ks], acc, 0, 0, 0);
    }
    const int d = h * HD + w * 16 + lr;
    #pragma unroll
    for (int j = 0; j < 4; ++j) {
      const int q = fm * 16 + 4 * g + j;
      if (q < LL) aout[(size_t)(b * LL + q) * DD + d] = (bf16)acc[j];
    }
  }
}

// ---------------- residual add + LayerNorm (one wave per row) ----------------
template<int WRITE_F32>
__global__ __launch_bounds__(64) void ln_kernel(
    const float* __restrict__ Y, const bf16* __restrict__ RES,
    const float* __restrict__ g, const float* __restrict__ bt,
    bf16* __restrict__ XB, float* __restrict__ XF) {
  const int row = blockIdx.x;
  const int lane = threadIdx.x;
  const size_t base = (size_t)row * DD + lane * 8;
  const float4 a0 = *(const float4*)(Y + base);
  const float4 a1 = *(const float4*)(Y + base + 4);
  const bf16x8 rv = *(const bf16x8*)(RES + base);
  float z[8];
  z[0] = a0.x + (float)rv[0]; z[1] = a0.y + (float)rv[1];
  z[2] = a0.z + (float)rv[2]; z[3] = a0.w + (float)rv[3];
  z[4] = a1.x + (float)rv[4]; z[5] = a1.y + (float)rv[5];
  z[6] = a1.z + (float)rv[6]; z[7] = a1.w + (float)rv[7];
  float s = 0.f, s2 = 0.f;
  #pragma unroll
  for (int j = 0; j < 8; ++j) { s += z[j]; s2 = fmaf(z[j], z[j], s2); }
  #pragma unroll
  for (int off = 32; off > 0; off >>= 1) {
    s  += __shfl_xor(s, off, 64);
    s2 += __shfl_xor(s2, off, 64);
  }
  const float mu = s * (1.f / 512.f);
  const float var = s2 * (1.f / 512.f) - mu * mu;
  const float inv = rsqrtf(var + 1e-5f);
  const int c = lane * 8;
  const float4 g0 = *(const float4*)(g + c),  g1 = *(const float4*)(g + c + 4);
  const float4 b0 = *(const float4*)(bt + c), b1 = *(const float4*)(bt + c + 4);
  float ov[8];
  ov[0] = (z[0] - mu) * inv * g0.x + b0.x; ov[1] = (z[1] - mu) * inv * g0.y + b0.y;
  ov[2] = (z[2] - mu) * inv * g0.z + b0.z; ov[3] = (z[3] - mu) * inv * g0.w + b0.w;
  ov[4] = (z[4] - mu) * inv * g1.x + b1.x; ov[5] = (z[5] - mu) * inv * g1.y + b1.y;
  ov[6] = (z[6] - mu) * inv * g1.z + b1.z; ov[7] = (z[7] - mu) * inv * g1.w + b1.w;
  bf16x8 pk;
  #pragma unroll
  for (int j = 0; j < 8; ++j) pk[j] = (bf16)ov[j];
  *(bf16x8*)(XB + base) = pk;
  if (WRITE_F32) {
    *(float4*)(XF + base)     = make_float4(ov[0], ov[1], ov[2], ov[3]);
    *(float4*)(XF + base + 4) = make_float4(ov[4], ov[5], ov[6], ov[7]);
  }
}

extern "C" void kernel_launch(void* const* d_in, const int* in_sizes, int n_in,
                              void* d_out, int out_size, void* d_ws, size_t ws_size,
                              hipStream_t stream) {
  const float* x_in   = (const float*)d_in[0];
  const int*   mask   = (const int*)d_in[1];
  const float* qkv_w  = (const float*)d_in[2];
  const float* fc_w   = (const float*)d_in[3];
  const float* fc_b   = (const float*)d_in[4];
  const float* ln1_g  = (const float*)d_in[5];
  const float* ln1_b  = (const float*)d_in[6];
  const float* ln2_g  = (const float*)d_in[7];
  const float* ln2_b  = (const float*)d_in[8];
  const float* ffn_w1 = (const float*)d_in[9];
  const float* ffn_b1 = (const float*)d_in[10];
  const float* ffn_w2 = (const float*)d_in[11];
  const float* ffn_b2 = (const float*)d_in[12];

  char* ws = (char*)d_ws;
  size_t off = 0;
  auto alloc = [&](size_t bytes) -> void* {
    off = (off + 255) & ~(size_t)255;
    void* p = ws + off;
    off += bytes;
    return p;
  };
  bf16*  XB   = (bf16*) alloc((size_t)MM * DD * 2);
  bf16*  BIGB = (bf16*) alloc((size_t)MM * FF * 2);
  float* PE   = (float*)alloc((size_t)LL * DD * 4);
  bf16*  WQKV = (bf16*) alloc((size_t)NLAYERS * DD * 3 * DD * 2);
  bf16*  WFC  = (bf16*) alloc((size_t)NLAYERS * DD * DD * 2);
  bf16*  W1T  = (bf16*) alloc((size_t)NLAYERS * DD * FF * 2);
  bf16*  W2T  = (bf16*) alloc((size_t)NLAYERS * FF * DD * 2);
  bf16*  AOUT = BIGB + (size_t)MM * (3 * DD);
  float* Y    = (float*)d_out;
  (void)ws_size; (void)in_sizes; (void)n_in; (void)out_size;

  pe_kernel<<<200, 256, 0, stream>>>(PE);
  transpose_cast<<<dim3(48, 16, NLAYERS), dim3(32, 8), 0, stream>>>(qkv_w,  WQKV, 512, 1536);
  transpose_cast<<<dim3(16, 16, NLAYERS), dim3(32, 8), 0, stream>>>(fc_w,   WFC,  512, 512);
  transpose_cast<<<dim3(64, 16, NLAYERS), dim3(32, 8), 0, stream>>>(ffn_w1, W1T,  512, 2048);
  transpose_cast<<<dim3(16, 64, NLAYERS), dim3(32, 8), 0, stream>>>(ffn_w2, W2T,  2048, 512);
  x0_kernel<<<12800, 256, 0, stream>>>(x_in, PE, XB);

  for (int i = 0; i < NLAYERS; ++i) {
    gemm_bt<1, 0><<<dim3(12, 200), 256, 0, stream>>>(
        XB, WQKV + (size_t)i * DD * 3 * DD, nullptr, BIGB, MM, 3 * DD, DD);
    attn_mfma<<<BB * NH, 256, 0, stream>>>(BIGB, mask, AOUT);
    gemm_bt<0, 0><<<dim3(4, 200), 256, 0, stream>>>(
        AOUT, WFC + (size_t)i * DD * DD, fc_b + i * DD, Y, MM, DD, DD);
    ln_kernel<0><<<MM, 64, 0, stream>>>(Y, XB, ln1_g + i * DD, ln1_b + i * DD, XB, nullptr);
    gemm_bt<1, 1><<<dim3(16, 200), 256, 0, stream>>>(
        XB, W1T + (size_t)i * DD * FF, ffn_b1 + i * FF, BIGB, MM, FF, DD);
    gemm_bt<0, 0><<<dim3(4, 200), 256, 0, stream>>>(
        BIGB, W2T + (size_t)i * FF * DD, ffn_b2 + i * DD, Y, MM, DD, FF);
    if (i == NLAYERS - 1)
      ln_kernel<1><<<MM, 64, 0, stream>>>(Y, XB, ln2_g + i * DD, ln2_b + i * DD,
                                          XB, (float*)d_out);
    else
      ln_kernel<0><<<MM, 64, 0, stream>>>(Y, XB, ln2_g + i * DD, ln2_b + i * DD, XB, nullptr);
  }
}

// Round 4
// 1235.664 us; speedup vs baseline: 1.8625x; 1.2193x over previous
//
#include <hip/hip_runtime.h>
#include <cstdint>
#include <cmath>

// Transformer encoder: B=256, L=100, D=512, F=2048, NL=4, H=8, hd=64.
// GEMMs + attention: bf16 MFMA (fp32 accum). Residual stream bf16; LN/softmax fp32.
// GEMM: 256x256 8-phase schedule (T1+T2+T3+T4+T5), 8 waves, BK=64, 128KB LDS.

#define NLAYERS 4
#define BB 256
#define LL 100
#define DD 512
#define FF 2048
#define NH 8
#define HD 64
#define MM (BB*LL)   // 25600 rows
#define ATT_R 112
#define ATT_K 128

typedef __bf16 bf16;
typedef bf16 bf16x8 __attribute__((ext_vector_type(8)));
typedef bf16 bf16x4 __attribute__((ext_vector_type(4)));
typedef float f32x4 __attribute__((ext_vector_type(4)));

__device__ __forceinline__ void load16(const void* g, void* l) {
  __builtin_amdgcn_global_load_lds(
      (const __attribute__((address_space(1))) void*)g,
      (__attribute__((address_space(3))) void*)l, 16, 0, 0);
}

// ---------------- positional encoding table [L][D] ----------------
__global__ void pe_kernel(float* __restrict__ pe) {
  const int idx = blockIdx.x * 256 + threadIdx.x;
  if (idx >= LL * DD) return;
  const int l = idx >> 9, d = idx & 511;
  const int i = d >> 1;
  const float div = expf((float)(2 * i) * (-9.210340371976184f / 512.f));
  const float ang = (float)l * div;
  pe[idx] = (d & 1) ? cosf(ang) : sinf(ang);
}

// ---------------- xb = bf16(2*x + pe) ----------------
__global__ __launch_bounds__(256) void x0_kernel(
    const float* __restrict__ xin, const float* __restrict__ pe,
    bf16* __restrict__ XB) {
  const size_t f = (size_t)blockIdx.x * 256 + threadIdx.x;
  const size_t e = f << 2;
  const int col  = (int)(e & 511);
  const int prow = (int)((e >> 9) % LL);
  const float4 xv = *(const float4*)(xin + e);
  const float4 pv = *(const float4*)(pe + (size_t)prow * DD + col);
  bf16x4 pk;
  pk[0] = (bf16)(2.f * xv.x + pv.x);
  pk[1] = (bf16)(2.f * xv.y + pv.y);
  pk[2] = (bf16)(2.f * xv.z + pv.z);
  pk[3] = (bf16)(2.f * xv.w + pv.w);
  *(bf16x4*)(XB + e) = pk;
}

// ---------------- weight cast + transpose: [K][N] f32 -> [N][K] bf16 ----------------
__global__ void transpose_cast(const float* __restrict__ src, bf16* __restrict__ dst,
                               int K, int N) {
  __shared__ float tile[32][33];
  const int z = blockIdx.z;
  src += (size_t)z * K * N;
  dst += (size_t)z * K * N;
  const int k0 = blockIdx.y * 32, n0 = blockIdx.x * 32;
  const int tx = threadIdx.x, ty = threadIdx.y;
  #pragma unroll
  for (int i = 0; i < 32; i += 8)
    tile[ty + i][tx] = src[(size_t)(k0 + ty + i) * N + n0 + tx];
  __syncthreads();
  #pragma unroll
  for (int i = 0; i < 32; i += 8)
    dst[(size_t)(n0 + ty + i) * K + k0 + tx] = (bf16)tile[tx][ty + i];
}

// ============ 256x256 8-phase GEMM: C[M,N] = A[M,K] @ Bt[N,K]^T ============
// 8 waves (2M x 4N), per-wave 128x64 output (acc[8][4] 16x16 frags), BK=64.
// LDS: 2 dbuf x 2 halves x (128 x 64 bf16) for A and B = 128 KB.
// Chunk layout: row r, col-block cb (8 bf16): byte = r*128 + ((cb^(r&7))*16)
// -> staged via pre-swizzled global source, linear LDS dest (global_load_lds).
// ds_read_b128: 16 rows x 4 slots, 2-way bank alias only (free).

__device__ __forceinline__ void stage_chunk(const bf16* __restrict__ src, int ldk,
                                            int grow0, int kt, bf16* chunk,
                                            int tid, int w) {
  const int rr = tid >> 3;                    // 0..63
  const int cb = (tid & 7) ^ (rr & 7);        // pre-swizzled logical col-block
  const bf16* g = src + (size_t)(grow0 + rr) * ldk + (kt << 6) + (cb << 3);
  load16(g, chunk + (w << 9));                       // rows 0-63 of chunk
  load16(g + ((size_t)ldk << 6), chunk + 4096 + (w << 9)); // rows 64-127
}

__device__ __forceinline__ bf16x8 lds_frag(const bf16* chunk, int lrow, int cb) {
  return *(const bf16x8*)(chunk + (lrow << 6) + ((cb ^ (lrow & 7)) << 3));
}

template<int OUT_BF16, int RELU>
__global__ __launch_bounds__(512) void gemm256(
    const bf16* __restrict__ A, const bf16* __restrict__ Bt,
    const float* __restrict__ bias, void* __restrict__ Cv,
    int N, int K) {
  __shared__ __align__(16) bf16 sA[2][2][128 * 64];
  __shared__ __align__(16) bf16 sB[2][2][128 * 64];
  const int tid = threadIdx.x;
  const int w = tid >> 6, lane = tid & 63;
  const int wr = w >> 2, wc = w & 3;           // wave grid 2M x 4N
  const int lr16 = lane & 15, lg = lane >> 4;  // frag row / k-group
  const int NT = K >> 6;

  // T1: bijective XCD-aware swizzle (x = N-tiles fastest -> A-panel L2 reuse)
  const int nwg = gridDim.x * gridDim.y;
  const int orig = blockIdx.y * gridDim.x + blockIdx.x;
  const int q = nwg >> 3, r = nwg & 7;
  const int xcd = orig & 7, lo = orig >> 3;
  const int swz = (xcd < r ? xcd * (q + 1) : r * (q + 1) + (xcd - r) * q) + lo;
  const int bn = (swz % gridDim.x) << 8;
  const int bm = (swz / gridDim.x) << 8;

  f32x4 acc[8][4] = {};
  bf16x8 Av[4][2], Bv0[2][2], Bv1[2][2];

  // prologue: A0(0) B0(0) A1(0) B1(0) A0(1) B0(1)  (12 loads/thread)
  stage_chunk(A,  K, bm,       0, sA[0][0], tid, w);
  stage_chunk(Bt, K, bn,       0, sB[0][0], tid, w);
  stage_chunk(A,  K, bm + 128, 0, sA[0][1], tid, w);
  stage_chunk(Bt, K, bn + 128, 0, sB[0][1], tid, w);
  stage_chunk(A,  K, bm,       1, sA[1][0], tid, w);
  stage_chunk(Bt, K, bn,       1, sB[1][0], tid, w);

  for (int t = 0; t < NT; ++t) {
    const int b = t & 1;
    // T4: counted vmcnt at tile boundary — keep 2 newest chunks in flight
    if (t < NT - 1) asm volatile("s_waitcnt vmcnt(4)" ::: "memory");
    else            asm volatile("s_waitcnt vmcnt(0)" ::: "memory");
    __builtin_amdgcn_s_barrier();

    // ---- phase 0: read A(mh0)+B(n0,n1); stage A1(t+1); MFMA quad (0,0)
    #pragma unroll
    for (int m = 0; m < 4; ++m) {
      const int lrow = m * 32 + wr * 16 + lr16;
      Av[m][0] = lds_frag(sA[b][0], lrow, lg);
      Av[m][1] = lds_frag(sA[b][0], lrow, 4 + lg);
    }
    #pragma unroll
    for (int n = 0; n < 2; ++n) {
      const int lrow = n * 64 + wc * 16 + lr16;
      Bv0[n][0] = lds_frag(sB[b][0], lrow, lg);
      Bv0[n][1] = lds_frag(sB[b][0], lrow, 4 + lg);
    }
    if (t + 1 < NT) stage_chunk(A, K, bm + 128, t + 1, sA[b ^ 1][1], tid, w);
    __builtin_amdgcn_s_barrier();
    __builtin_amdgcn_s_setprio(1);
    #pragma unroll
    for (int m = 0; m < 4; ++m)
      #pragma unroll
      for (int n = 0; n < 2; ++n) {
        acc[m][n] = __builtin_amdgcn_mfma_f32_16x16x32_bf16(Av[m][0], Bv0[n][0], acc[m][n], 0, 0, 0);
        acc[m][n] = __builtin_amdgcn_mfma_f32_16x16x32_bf16(Av[m][1], Bv0[n][1], acc[m][n], 0, 0, 0);
      }
    __builtin_amdgcn_s_setprio(0);
    __builtin_amdgcn_s_barrier();

    // ---- phase 1: read B(n2,n3); stage B1(t+1); MFMA quad (0,1)
    #pragma unroll
    for (int n = 0; n < 2; ++n) {
      const int lrow = n * 64 + wc * 16 + lr16;
      Bv1[n][0] = lds_frag(sB[b][1], lrow, lg);
      Bv1[n][1] = lds_frag(sB[b][1], lrow, 4 + lg);
    }
    if (t + 1 < NT) stage_chunk(Bt, K, bn + 128, t + 1, sB[b ^ 1][1], tid, w);
    __builtin_amdgcn_s_barrier();
    __builtin_amdgcn_s_setprio(1);
    #pragma unroll
    for (int m = 0; m < 4; ++m)
      #pragma unroll
      for (int n = 0; n < 2; ++n) {
        acc[m][n + 2] = __builtin_amdgcn_mfma_f32_16x16x32_bf16(Av[m][0], Bv1[n][0], acc[m][n + 2], 0, 0, 0);
        acc[m][n + 2] = __builtin_amdgcn_mfma_f32_16x16x32_bf16(Av[m][1], Bv1[n][1], acc[m][n + 2], 0, 0, 0);
      }
    __builtin_amdgcn_s_setprio(0);
    __builtin_amdgcn_s_barrier();

    // ---- phase 2: read A(mh1); stage A0(t+2); MFMA quad (1,0)
    #pragma unroll
    for (int m = 0; m < 4; ++m) {
      const int lrow = m * 32 + wr * 16 + lr16;
      Av[m][0] = lds_frag(sA[b][1], lrow, lg);
      Av[m][1] = lds_frag(sA[b][1], lrow, 4 + lg);
    }
    if (t + 2 < NT) stage_chunk(A, K, bm, t + 2, sA[b][0], tid, w);
    __builtin_amdgcn_s_barrier();
    __builtin_amdgcn_s_setprio(1);
    #pragma unroll
    for (int m = 0; m < 4; ++m)
      #pragma unroll
      for (int n = 0; n < 2; ++n) {
        acc[m + 4][n] = __builtin_amdgcn_mfma_f32_16x16x32_bf16(Av[m][0], Bv0[n][0], acc[m + 4][n], 0, 0, 0);
        acc[m + 4][n] = __builtin_amdgcn_mfma_f32_16x16x32_bf16(Av[m][1], Bv0[n][1], acc[m + 4][n], 0, 0, 0);
      }
    __builtin_amdgcn_s_setprio(0);
    __builtin_amdgcn_s_barrier();

    // ---- phase 3: stage B0(t+2); MFMA quad (1,1)
    if (t + 2 < NT) stage_chunk(Bt, K, bn, t + 2, sB[b][0], tid, w);
    __builtin_amdgcn_s_barrier();
    __builtin_amdgcn_s_setprio(1);
    #pragma unroll
    for (int m = 0; m < 4; ++m)
      #pragma unroll
      for (int n = 0; n < 2; ++n) {
        acc[m + 4][n + 2] = __builtin_amdgcn_mfma_f32_16x16x32_bf16(Av[m][0], Bv1[n][0], acc[m + 4][n + 2], 0, 0, 0);
        acc[m + 4][n + 2] = __builtin_amdgcn_mfma_f32_16x16x32_bf16(Av[m][1], Bv1[n][1], acc[m + 4][n + 2], 0, 0, 0);
      }
    __builtin_amdgcn_s_setprio(0);
    // loop-top vmcnt + barrier closes the tile
  }

  // epilogue: C row = bm + m*32 + wr*16 + g*4 + j ; col = bn + n*64 + wc*16 + lr16
  const int g4 = (lane >> 4) << 2;
  #pragma unroll
  for (int n = 0; n < 4; ++n) {
    const int col = bn + n * 64 + wc * 16 + lr16;
    const float bvv = bias ? bias[col] : 0.f;
    #pragma unroll
    for (int m = 0; m < 8; ++m) {
      const int row = bm + m * 32 + wr * 16 + g4;
      #pragma unroll
      for (int j = 0; j < 4; ++j) {
        float v = acc[m][n][j] + bvv;
        if (RELU) v = fmaxf(v, 0.f);
        if (OUT_BF16) ((bf16*)Cv)[(size_t)(row + j) * N + col] = (bf16)v;
        else          ((float*)Cv)[(size_t)(row + j) * N + col] = v;
      }
    }
  }
}

// ---------------- MFMA attention: one block (4 waves) per (b,h) ----------------
__global__ __launch_bounds__(256) void attn_mfma(
    const bf16* __restrict__ qkv, const int* __restrict__ mask,
    bf16* __restrict__ aout) {
  __shared__ __align__(16) bf16 sQ[ATT_R * 64];
  __shared__ __align__(16) bf16 sK[ATT_R * 64];
  __shared__ __align__(16) bf16 sVt[64 * 136];
  __shared__ __align__(16) bf16 sP[ATT_R * ATT_K];
  __shared__ int sM[ATT_R];
  const int bh = blockIdx.x, b = bh >> 3, h = bh & 7;
  const int tid = threadIdx.x, w = tid >> 6, lane = tid & 63;
  const int lr = lane & 15;
  const int lk = (lane >> 4) << 3;
  const int g  = lane >> 4;

  for (int i = tid; i < ATT_R * 64 / 8; i += 256) { ((int4*)sQ)[i] = int4{0,0,0,0}; ((int4*)sK)[i] = int4{0,0,0,0}; }
  for (int i = tid; i < 64 * 136 / 8; i += 256) ((int4*)sVt)[i] = int4{0,0,0,0};
  for (int i = tid; i < ATT_R * ATT_K / 8; i += 256) ((int4*)sP)[i] = int4{0,0,0,0};
  __syncthreads();

  const bf16* base = qkv + (size_t)(b * LL) * (3 * DD) + h * HD;
  for (int c = tid; c < LL * 8; c += 256) {
    const int l = c >> 3, u = c & 7;
    const bf16x8 qv = *(const bf16x8*)(base + (size_t)l * (3 * DD) + u * 8);
    const bf16x8 kv = *(const bf16x8*)(base + (size_t)l * (3 * DD) + DD + u * 8);
    const bf16x8 vv = *(const bf16x8*)(base + (size_t)l * (3 * DD) + 2 * DD + u * 8);
    const int qb = (l * 128 + u * 16) ^ ((l & 7) << 4);
    *(bf16x8*)((char*)sQ + qb) = qv;
    *(bf16x8*)((char*)sK + qb) = kv;
    #pragma unroll
    for (int j = 0; j < 8; ++j) sVt[(u * 8 + j) * 136 + l] = vv[j];
  }
  if (tid < ATT_R) sM[tid] = (tid < LL) ? mask[b * LL + tid] : 0;
  __syncthreads();

  #pragma unroll
  for (int fi = 0; fi < 2; ++fi) {
    const int fm = w + fi * 4;
    if (fm >= 7) continue;
    const int ar = fm * 16 + lr;
    const int abase = ar * 128;
    const int aswz = (ar & 7) << 4;
    const bf16x8 a0 = *(const bf16x8*)((char*)sQ + ((abase + lk * 2) ^ aswz));
    const bf16x8 a1 = *(const bf16x8*)((char*)sQ + ((abase + 64 + lk * 2) ^ aswz));
    f32x4 s[7];
    #pragma unroll
    for (int fn = 0; fn < 7; ++fn) {
      const int br = fn * 16 + lr;
      const int bswz = (br & 7) << 4;
      const bf16x8 b0 = *(const bf16x8*)((char*)sK + ((br * 128 + lk * 2) ^ bswz));
      const bf16x8 b1 = *(const bf16x8*)((char*)sK + ((br * 128 + 64 + lk * 2) ^ bswz));
      f32x4 acc = {};
      acc = __builtin_amdgcn_mfma_f32_16x16x32_bf16(a0, b0, acc, 0, 0, 0);
      acc = __builtin_amdgcn_mfma_f32_16x16x32_bf16(a1, b1, acc, 0, 0, 0);
      s[fn] = acc;
    }
    #pragma unroll
    for (int fn = 0; fn < 7; ++fn) {
      if (sM[fn * 16 + lr] == 0) {
        s[fn][0] = -INFINITY; s[fn][1] = -INFINITY;
        s[fn][2] = -INFINITY; s[fn][3] = -INFINITY;
      }
    }
    float sm[4];
    #pragma unroll
    for (int j = 0; j < 4; ++j) {
      float m = s[0][j];
      #pragma unroll
      for (int fn = 1; fn < 7; ++fn) m = fmaxf(m, s[fn][j]);
      #pragma unroll
      for (int off = 1; off < 16; off <<= 1) m = fmaxf(m, __shfl_xor(m, off, 64));
      float t = 0.f;
      #pragma unroll
      for (int fn = 0; fn < 7; ++fn) { const float p = __expf(s[fn][j] - m); s[fn][j] = p; t += p; }
      #pragma unroll
      for (int off = 1; off < 16; off <<= 1) t += __shfl_xor(t, off, 64);
      sm[j] = 1.f / t;
    }
    #pragma unroll
    for (int fn = 0; fn < 7; ++fn) {
      const int k = fn * 16 + lr;
      #pragma unroll
      for (int j = 0; j < 4; ++j) {
        const int rr = fm * 16 + 4 * g + j;
        const int byte = (rr * 256 + k * 2) ^ ((rr & 7) << 4);
        *(bf16*)((char*)sP + byte) = (bf16)(s[fn][j] * sm[j]);
      }
    }
  }
  __syncthreads();

  bf16x8 bV[4];
  #pragma unroll
  for (int ks = 0; ks < 4; ++ks)
    bV[ks] = *(const bf16x8*)((char*)sVt + ((w * 16 + lr) * 272 + ks * 64 + lk * 2));
  #pragma unroll
  for (int fm = 0; fm < 7; ++fm) {
    f32x4 acc = {};
    const int ar = fm * 16 + lr;
    const int aswz = (ar & 7) << 4;
    #pragma unroll
    for (int ks = 0; ks < 4; ++ks) {
      const bf16x8 aP = *(const bf16x8*)((char*)sP + ((ar * 256 + ks * 64 + lk * 2) ^ aswz));
      acc = __builtin_amdgcn_mfma_f32_16x16x32_bf16(aP, bV[ks], acc, 0, 0, 0);
    }
    const int d = h * HD + w * 16 + lr;
    #pragma unroll
    for (int j = 0; j < 4; ++j) {
      const int qr = fm * 16 + 4 * g + j;
      if (qr < LL) aout[(size_t)(b * LL + qr) * DD + d] = (bf16)acc[j];
    }
  }
}

// ---------------- residual add + LayerNorm (one wave per row) ----------------
template<int WRITE_F32>
__global__ __launch_bounds__(64) void ln_kernel(
    const float* __restrict__ Y, const bf16* __restrict__ RES,
    const float* __restrict__ g, const float* __restrict__ bt,
    bf16* __restrict__ XB, float* __restrict__ XF) {
  const int row = blockIdx.x;
  const int lane = threadIdx.x;
  const size_t base = (size_t)row * DD + lane * 8;
  const float4 a0 = *(const float4*)(Y + base);
  const float4 a1 = *(const float4*)(Y + base + 4);
  const bf16x8 rv = *(const bf16x8*)(RES + base);
  float z[8];
  z[0] = a0.x + (float)rv[0]; z[1] = a0.y + (float)rv[1];
  z[2] = a0.z + (float)rv[2]; z[3] = a0.w + (float)rv[3];
  z[4] = a1.x + (float)rv[4]; z[5] = a1.y + (float)rv[5];
  z[6] = a1.z + (float)rv[6]; z[7] = a1.w + (float)rv[7];
  float s = 0.f, s2 = 0.f;
  #pragma unroll
  for (int j = 0; j < 8; ++j) { s += z[j]; s2 = fmaf(z[j], z[j], s2); }
  #pragma unroll
  for (int off = 32; off > 0; off >>= 1) {
    s  += __shfl_xor(s, off, 64);
    s2 += __shfl_xor(s2, off, 64);
  }
  const float mu = s * (1.f / 512.f);
  const float var = s2 * (1.f / 512.f) - mu * mu;
  const float inv = rsqrtf(var + 1e-5f);
  const int c = lane * 8;
  const float4 g0 = *(const float4*)(g + c),  g1 = *(const float4*)(g + c + 4);
  const float4 b0 = *(const float4*)(bt + c), b1 = *(const float4*)(bt + c + 4);
  float ov[8];
  ov[0] = (z[0] - mu) * inv * g0.x + b0.x; ov[1] = (z[1] - mu) * inv * g0.y + b0.y;
  ov[2] = (z[2] - mu) * inv * g0.z + b0.z; ov[3] = (z[3] - mu) * inv * g0.w + b0.w;
  ov[4] = (z[4] - mu) * inv * g1.x + b1.x; ov[5] = (z[5] - mu) * inv * g1.y + b1.y;
  ov[6] = (z[6] - mu) * inv * g1.z + b1.z; ov[7] = (z[7] - mu) * inv * g1.w + b1.w;
  bf16x8 pk;
  #pragma unroll
  for (int j = 0; j < 8; ++j) pk[j] = (bf16)ov[j];
  *(bf16x8*)(XB + base) = pk;
  if (WRITE_F32) {
    *(float4*)(XF + base)     = make_float4(ov[0], ov[1], ov[2], ov[3]);
    *(float4*)(XF + base + 4) = make_float4(ov[4], ov[5], ov[6], ov[7]);
  }
}

extern "C" void kernel_launch(void* const* d_in, const int* in_sizes, int n_in,
                              void* d_out, int out_size, void* d_ws, size_t ws_size,
                              hipStream_t stream) {
  const float* x_in   = (const float*)d_in[0];
  const int*   mask   = (const int*)d_in[1];
  const float* qkv_w  = (const float*)d_in[2];
  const float* fc_w   = (const float*)d_in[3];
  const float* fc_b   = (const float*)d_in[4];
  const float* ln1_g  = (const float*)d_in[5];
  const float* ln1_b  = (const float*)d_in[6];
  const float* ln2_g  = (const float*)d_in[7];
  const float* ln2_b  = (const float*)d_in[8];
  const float* ffn_w1 = (const float*)d_in[9];
  const float* ffn_b1 = (const float*)d_in[10];
  const float* ffn_w2 = (const float*)d_in[11];
  const float* ffn_b2 = (const float*)d_in[12];

  char* ws = (char*)d_ws;
  size_t off = 0;
  auto alloc = [&](size_t bytes) -> void* {
    off = (off + 255) & ~(size_t)255;
    void* p = ws + off;
    off += bytes;
    return p;
  };
  bf16*  XB   = (bf16*) alloc((size_t)MM * DD * 2);
  bf16*  BIGB = (bf16*) alloc((size_t)MM * FF * 2);
  float* PE   = (float*)alloc((size_t)LL * DD * 4);
  bf16*  WQKV = (bf16*) alloc((size_t)NLAYERS * DD * 3 * DD * 2);
  bf16*  WFC  = (bf16*) alloc((size_t)NLAYERS * DD * DD * 2);
  bf16*  W1T  = (bf16*) alloc((size_t)NLAYERS * DD * FF * 2);
  bf16*  W2T  = (bf16*) alloc((size_t)NLAYERS * FF * DD * 2);
  bf16*  AOUT = BIGB + (size_t)MM * (3 * DD);
  float* Y    = (float*)d_out;
  (void)ws_size; (void)in_sizes; (void)n_in; (void)out_size;

  pe_kernel<<<200, 256, 0, stream>>>(PE);
  transpose_cast<<<dim3(48, 16, NLAYERS), dim3(32, 8), 0, stream>>>(qkv_w,  WQKV, 512, 1536);
  transpose_cast<<<dim3(16, 16, NLAYERS), dim3(32, 8), 0, stream>>>(fc_w,   WFC,  512, 512);
  transpose_cast<<<dim3(64, 16, NLAYERS), dim3(32, 8), 0, stream>>>(ffn_w1, W1T,  512, 2048);
  transpose_cast<<<dim3(16, 64, NLAYERS), dim3(32, 8), 0, stream>>>(ffn_w2, W2T,  2048, 512);
  x0_kernel<<<12800, 256, 0, stream>>>(x_in, PE, XB);

  for (int i = 0; i < NLAYERS; ++i) {
    // qkv = xb @ qkv_w -> bf16 [M,1536]
    gemm256<1, 0><<<dim3(6, 100), 512, 0, stream>>>(
        XB, WQKV + (size_t)i * DD * 3 * DD, nullptr, BIGB, 3 * DD, DD);
    attn_mfma<<<BB * NH, 256, 0, stream>>>(BIGB, mask, AOUT);
    // attn proj + bias -> fp32 Y
    gemm256<0, 0><<<dim3(2, 100), 512, 0, stream>>>(
        AOUT, WFC + (size_t)i * DD * DD, fc_b + i * DD, Y, DD, DD);
    ln_kernel<0><<<MM, 64, 0, stream>>>(Y, XB, ln1_g + i * DD, ln1_b + i * DD, XB, nullptr);
    // h = relu(x @ w1 + b1) -> bf16 [M,2048]
    gemm256<1, 1><<<dim3(8, 100), 512, 0, stream>>>(
        XB, W1T + (size_t)i * DD * FF, ffn_b1 + i * FF, BIGB, FF, DD);
    // y = h @ w2 + b2 -> fp32 Y
    gemm256<0, 0><<<dim3(2, 100), 512, 0, stream>>>(
        BIGB, W2T + (size_t)i * FF * DD, ffn_b2 + i * DD, Y, DD, FF);
    if (i == NLAYERS - 1)
      ln_kernel<1><<<MM, 64, 0, stream>>>(Y, XB, ln2_g + i * DD, ln2_b + i * DD,
                                          XB, (float*)d_out);
    else
      ln_kernel<0><<<MM, 64, 0, stream>>>(Y, XB, ln2_g + i * DD, ln2_b + i * DD, XB, nullptr);
  }
}